// Round 7
// baseline (197.883 us; speedup 1.0000x reference)
//
#include <hip/hip_runtime.h>

// Bilateral 5x5, 3 chained passes FUSED into one kernel.
// [32,1,512,512] fp32, replicate padding, w = exp2(dr^2*nax + dc^2*nay + d^2*ncr).
//
// Round-6 counters: kernel 89 us, VALUBusy 74% -> ~66 us of VALU issue, of
// which only ~31 us is tap-core (5 VALU + 1 exp per tap). Round 7 attacks
// the rest:
//  - 2-row units: 4 cols x 2 rows per unit; the 4 window rows (12 quads,
//    aligned b128) are shared by both output rows (6 quads/row vs 7, half
//    the per-output addressing). Pass 3 = exactly 256 units (no loop).
//  - packed fp32: tap core on float2 ext-vectors -> v_pk_{add,mul,fma}_f32,
//    2.5 VALU-slots/px instead of 5. exp2 stays scalar (quarter-rate pipe).
//  - __launch_bounds__(256,5): LDS (29.6 KB) caps at 5 blocks/CU; keep
//    VGPR <= ~102 so occupancy stays 5 waves/SIMD.
//
// Geometry (every pass reads 16B-aligned LDS quads, center at (r+2, 4q+4)):
//   buf0 staged input : rows [Y0-6,Y0+37] x cols [X0-12,X0+79]  44 x 92
//   buf1 = pass1 out  : rows [Y0-4,Y0+35] x cols [X0- 8,X0+75]  40 x 84
//   buf2 = pass2 out  : rows [Y0-2,Y0+33] x cols [X0- 4,X0+71]  36 x 76 (aliases buf0)
// Staging clamps global coords (buf0 replicate-padded exactly); after
// pass1/pass2 replicate_fill() restores replicate padding of intermediates
// in border blocks (the reference pads each intermediate image).
//
// Pruning (round 3): taps with spatial log2-weight < TH2 are skipped via
// block-uniform branches -> effective 3x3 for sigma=0.5 (8 exps/px).
// Generic 5x5 path kept for large sigma.

typedef float v2f __attribute__((ext_vector_type(2)));

#define EXP2(x) __builtin_amdgcn_exp2f(x)
#define RCP(x)  __builtin_amdgcn_rcpf(x)
#define TH2 (-10.0f)

#define TILE_X 64
#define TILE_Y 32
#define S0R 44
#define S0C 92            // 368 B row stride (16B-aligned)
#define S1R 40
#define S1C 84            // 336 B
#define S2R 36
#define S2C 76            // 304 B

// Copy replicate-padding into phantom slots of an LDS image.
// Valid region [rlo,rhi]x[vlo,vhi]; reads valid slots, writes phantom slots
// -> race-free without an internal barrier. Block-uniform early-out.
template<int NR, int NC>
__device__ __forceinline__ void replicate_fill(float* buf, int rlo, int rhi,
                                               int vlo, int vhi, int tid)
{
    if (rlo == 0 && vlo == 0 && rhi == NR - 1 && vhi == NC - 1) return;
    for (int t = tid; t < NR * NC; t += 256) {
        const int r = t / NC, v = t - r * NC;
        const int rs = min(max(r, rlo), rhi);
        const int vs = min(max(v, vlo), vhi);
        if (rs != r || vs != v) buf[r * NC + v] = buf[rs * NC + vs];
    }
}

// 6-wide window row (cols c-1 .. c+4) built from 3 aligned quads.
struct Row6 { float w0, w1, w2, w3, w4, w5; };

__device__ __forceinline__ Row6 mkrow(const float* p)
{
    const float4 L = *(const float4*)p;
    const float4 M = *(const float4*)(p + 4);
    const float4 R = *(const float4*)(p + 8);
    Row6 r; r.w0 = L.w; r.w1 = M.x; r.w2 = M.y; r.w3 = M.z; r.w4 = M.w;
    r.w5 = R.x;
    return r;
}

// One bilateral pass over a tile held in LDS. Unit t -> (row-pair rp, quad q);
// output rows 2rp, 2rp+1 at cols 4q..4q+3; centers at src (2rp+2..3, 4q+4).
template<int NQ, int NR, int SST, int DSTST, bool TOG>
__device__ __forceinline__ void bilat_tile_pass(
    const float* __restrict__ src, float* __restrict__ dst,
    float* __restrict__ gout, int W,
    int tid, float ncr, float nax, float nay, bool prune)
{
    const v2f ncr2 = {ncr, ncr};
    constexpr int NU = NQ * (NR / 2);
    for (int t = tid; t < NU; t += 256) {
        const int rp = t / NQ;
        const int q  = t - rp * NQ;
        const int rA = 2 * rp;
        const float* base = src + (rA + 1) * SST + 4 * q;  // src row rA+1

        auto store_row = [&](int r, v2f n0, v2f n1, v2f d0, v2f d1) {
            float4 o;
            o.x = n0.x * RCP(d0.x);
            o.y = n0.y * RCP(d0.y);
            o.z = n1.x * RCP(d1.x);
            o.w = n1.y * RCP(d1.y);
            if (TOG) *(float4*)(gout + r * W + 4 * q) = o;
            else     *(float4*)(dst + r * DSTST + 4 * q) = o;
        };

        if (prune) {
            // packed 2-px tap: 5 v_pk ops + 2 exp for 2 pixels
            auto tapp = [&](v2f nb, v2f cen, v2f& num, v2f& den, float b) {
                v2f d  = nb - cen;
                v2f tt = __builtin_elementwise_fma(d * d, ncr2, (v2f){b, b});
                v2f w  = {EXP2(tt.x), EXP2(tt.y)};
                num = __builtin_elementwise_fma(w, nb, num);
                den += w;
            };
            // off-center row: taps dc=-1,0,+1 for both px pairs
            auto row_full = [&](const Row6& r, v2f c0, v2f c1,
                                v2f& n0, v2f& n1, v2f& d0, v2f& d1) {
                const float bd = nax + nay;
                tapp((v2f){r.w0, r.w1}, c0, n0, d0, bd);   // dc=-1
                tapp((v2f){r.w2, r.w3}, c1, n1, d1, bd);
                tapp((v2f){r.w1, r.w2}, c0, n0, d0, nax);  // dc=0
                tapp((v2f){r.w3, r.w4}, c1, n1, d1, nax);
                tapp((v2f){r.w2, r.w3}, c0, n0, d0, bd);   // dc=+1
                tapp((v2f){r.w4, r.w5}, c1, n1, d1, bd);
            };
            // center row: taps dc=-1,+1 only (center tap folded into init)
            auto row_ctr = [&](const Row6& r, v2f c0, v2f c1,
                               v2f& n0, v2f& n1, v2f& d0, v2f& d1) {
                tapp((v2f){r.w0, r.w1}, c0, n0, d0, nay);  // dc=-1
                tapp((v2f){r.w2, r.w3}, c1, n1, d1, nay);
                tapp((v2f){r.w2, r.w3}, c0, n0, d0, nay);  // dc=+1
                tapp((v2f){r.w4, r.w5}, c1, n1, d1, nay);
            };

            const Row6 r0 = mkrow(base);
            const Row6 r1 = mkrow(base + SST);
            const Row6 r2 = mkrow(base + 2 * SST);

            // ---- output row A (center = src row rA+2 = r1) ----
            {
                v2f c0 = {r1.w1, r1.w2}, c1 = {r1.w3, r1.w4};
                v2f n0 = c0, n1 = c1;
                v2f d0 = {1.f, 1.f}, d1 = {1.f, 1.f};
                row_ctr (r1, c0, c1, n0, n1, d0, d1);
                row_full(r0, c0, c1, n0, n1, d0, d1);
                row_full(r2, c0, c1, n0, n1, d0, d1);
                store_row(rA, n0, n1, d0, d1);
            }
            // ---- output row B (center = src row rA+3 = r2) ----
            {
                const Row6 r3 = mkrow(base + 3 * SST);
                v2f c0 = {r2.w1, r2.w2}, c1 = {r2.w3, r2.w4};
                v2f n0 = c0, n1 = c1;
                v2f d0 = {1.f, 1.f}, d1 = {1.f, 1.f};
                row_ctr (r2, c0, c1, n0, n1, d0, d1);
                row_full(r1, c0, c1, n0, n1, d0, d1);
                row_full(r3, c0, c1, n0, n1, d0, d1);
                store_row(rA + 1, n0, n1, d0, d1);
            }
        } else {
            // generic 5x5 with per-tap uniform pruning (cold path)
            #pragma unroll
            for (int s = 0; s < 2; ++s) {
                const int r = rA + s;
                const float* cp = src + (r + 2) * SST + 4 * q + 4;
                const float4 M0 = *(const float4*)cp;
                float cen[4] = {M0.x, M0.y, M0.z, M0.w};
                float num[4] = {M0.x, M0.y, M0.z, M0.w};
                float den[4] = {1.f, 1.f, 1.f, 1.f};
                #pragma unroll
                for (int dr = -2; dr <= 2; ++dr) {
                    const float ra = (float)(dr * dr) * nax;
                    const float rbest = dr ? ra : nay;
                    if (rbest < TH2) continue;
                    const float* rp2 = cp + dr * SST;
                    const float4 Lq = *(const float4*)(rp2 - 4);
                    const float4 Mq = *(const float4*)(rp2);
                    const float4 Rq = *(const float4*)(rp2 + 4);
                    const float w8[8] = {Lq.z, Lq.w, Mq.x, Mq.y, Mq.z, Mq.w,
                                         Rq.x, Rq.y};
                    #pragma unroll
                    for (int dc = -2; dc <= 2; ++dc) {
                        if (dr == 0 && dc == 0) continue;
                        const float b = ra + (float)(dc * dc) * nay;
                        if (b < TH2) continue;
                        #pragma unroll
                        for (int j = 0; j < 4; ++j) {
                            const float nb = w8[2 + j + dc];
                            const float d  = nb - cen[j];
                            const float tt = fmaf(d * d, ncr, b);
                            const float w  = EXP2(tt);
                            num[j] = fmaf(w, nb, num[j]);
                            den[j] += w;
                        }
                    }
                }
                float4 o;
                o.x = num[0] * RCP(den[0]);
                o.y = num[1] * RCP(den[1]);
                o.z = num[2] * RCP(den[2]);
                o.w = num[3] * RCP(den[3]);
                if (TOG) *(float4*)(gout + r * W + 4 * q) = o;
                else     *(float4*)(dst + r * DSTST + 4 * q) = o;
            }
        }
    }
}

__global__ __launch_bounds__(256, 5)
void bilat3_fused(const float* __restrict__ in, float* __restrict__ out,
                  const float* __restrict__ sxyz, const float* __restrict__ srr,
                  int H, int W)
{
    __shared__ __align__(16) float buf0[S0R * S0C];   // 16192 B
    __shared__ __align__(16) float buf1[S1R * S1C];   // 13440 B -> 29.6 KB

    const int tid = threadIdx.x;
    const int X0 = blockIdx.x * TILE_X;
    const int Y0 = blockIdx.y * TILE_Y;
    const size_t img_off = (size_t)blockIdx.z * (size_t)H * (size_t)W;
    const float* __restrict__ img = in + img_off;

    // per-pass constants, -log2e pre-folded
    const float L2E = 1.4426950408889634f;
    float ncr[3], nax[3], nay[3];
    bool prune[3];
    #pragma unroll
    for (int p = 0; p < 3; ++p) {
        const float sx = sxyz[2 * p], sy = sxyz[2 * p + 1], sr = srr[p];
        ncr[p] = -0.5f / (sr * sr) * L2E;
        nax[p] = -0.5f / (sx * sx) * L2E;
        nay[p] = -0.5f / (sy * sy) * L2E;
        prune[p] = (4.f * nax[p] < TH2) && (4.f * nay[p] < TH2);
    }

    // ---- stage buf0: replicate-clamped input aperture ----
    {
        const int NQ0 = S0C / 4;  // 23 quads/row
        #pragma unroll
        for (int t = tid; t < S0R * NQ0; t += 256) {
            const int r = t / NQ0, k = t - r * NQ0;
            const int gy = Y0 - 6 + r;
            const int gx = X0 - 12 + 4 * k;
            float4 v;
            if (gy >= 0 && gy < H && gx >= 0 && gx + 3 < W) {
                v = *(const float4*)(img + (size_t)gy * W + gx);  // aligned
            } else {
                const size_t rb = (size_t)min(max(gy, 0), H - 1) * W;
                v.x = img[rb + min(max(gx    , 0), W - 1)];
                v.y = img[rb + min(max(gx + 1, 0), W - 1)];
                v.z = img[rb + min(max(gx + 2, 0), W - 1)];
                v.w = img[rb + min(max(gx + 3, 0), W - 1)];
            }
            *(float4*)(buf0 + r * S0C + 4 * k) = v;
        }
    }
    __syncthreads();

    // ---- pass 1: buf0 -> buf1 ----
    bilat_tile_pass<S1C / 4, S1R, S0C, S1C, false>(
        buf0, buf1, nullptr, W, tid, ncr[0], nax[0], nay[0], prune[0]);
    __syncthreads();
    replicate_fill<S1R, S1C>(buf1,
        max(0, 4 - Y0), min(S1R - 1, (H - 1) - (Y0 - 4)),
        max(0, 8 - X0), min(S1C - 1, (W - 1) - (X0 - 8)), tid);
    __syncthreads();

    // ---- pass 2: buf1 -> buf2 (aliases buf0; staged input is dead) ----
    float* buf2 = buf0;
    bilat_tile_pass<S2C / 4, S2R, S1C, S2C, false>(
        buf1, buf2, nullptr, W, tid, ncr[1], nax[1], nay[1], prune[1]);
    __syncthreads();
    replicate_fill<S2R, S2C>(buf2,
        max(0, 2 - Y0), min(S2R - 1, (H - 1) - (Y0 - 2)),
        max(0, 4 - X0), min(S2C - 1, (W - 1) - (X0 - 4)), tid);
    __syncthreads();

    // ---- pass 3: buf2 -> global (exactly 256 units, single iteration) ----
    float* gout = out + img_off + (size_t)Y0 * W + X0;
    bilat_tile_pass<TILE_X / 4, TILE_Y, S2C, 0, true>(
        buf2, nullptr, gout, W, tid, ncr[2], nax[2], nay[2], prune[2]);
}

extern "C" void kernel_launch(void* const* d_in, const int* in_sizes, int n_in,
                              void* d_out, int out_size, void* d_ws, size_t ws_size,
                              hipStream_t stream)
{
    const float* x    = (const float*)d_in[0];
    const float* sxyz = (const float*)d_in[1];   // [3,2]
    const float* sr   = (const float*)d_in[2];   // [3]
    float* out = (float*)d_out;
    (void)d_ws; (void)ws_size;

    const int H = 512, W = 512;
    const int BC = in_sizes[0] / (H * W);        // 32

    dim3 block(256);
    dim3 grid(W / TILE_X, H / TILE_Y, BC);       // 8 x 16 x 32 = 4096 blocks

    bilat3_fused<<<grid, block, 0, stream>>>(x, out, sxyz, sr, H, W);
}

// Round 8
// 145.020 us; speedup vs baseline: 1.3645x; 1.3645x over previous
//
#include <hip/hip_runtime.h>

// Bilateral 5x5, 3 chained passes FUSED into one kernel.
// [32,1,512,512] fp32, replicate padding, w = exp2(dr^2*nax + dc^2*nay + d^2*ncr).
//
// Round-7 post-mortem: 2-row units + packed core + __launch_bounds__(256,5)
// spilled to scratch (WRITE_SIZE 32->336 MB, VALUBusy 35%, kernel 138 us).
// Round 8 = round-6 structure (89 us, no spills) + ONE change: the pruned
// tap core is packed on float2 ext-vectors (v_pk_add/mul/fma_f32), 5 packed
// ops per 2 pixels instead of 10 scalar. Single-row 4-px units keep the
// live set ~40 VGPRs; plain __launch_bounds__(256) (LDS caps occupancy at
// 5 blocks/CU anyway -- the (256,5) VGPR cap is what forced round-7 spills).
//
// Geometry (every pass reads 16B-aligned LDS quads, center at (r+2, 4q+4)):
//   buf0 staged input : rows [Y0-6,Y0+37] x cols [X0-12,X0+79]  44 x 92
//   buf1 = pass1 out  : rows [Y0-4,Y0+35] x cols [X0- 8,X0+75]  40 x 84
//   buf2 = pass2 out  : rows [Y0-2,Y0+33] x cols [X0- 4,X0+71]  36 x 76 (aliases buf0)
// Staging clamps global coords (buf0 replicate-padded exactly); after
// pass1/pass2 replicate_fill() restores replicate padding of intermediates
// in border blocks (the reference pads each intermediate image).
//
// Pruning (round 3): taps with spatial log2-weight < TH2 skipped via
// block-uniform branches -> effective 3x3 for sigma=0.5 (8 exps/px).
// Generic 5x5 path kept for large sigma.

typedef float v2f __attribute__((ext_vector_type(2)));

#define EXP2(x) __builtin_amdgcn_exp2f(x)
#define RCP(x)  __builtin_amdgcn_rcpf(x)
#define TH2 (-10.0f)

#define TILE_X 64
#define TILE_Y 32
#define S0R 44
#define S0C 92            // 368 B row stride (16B-aligned)
#define S1R 40
#define S1C 84            // 336 B
#define S2R 36
#define S2C 76            // 304 B

// Copy replicate-padding into phantom slots of an LDS image.
// Valid region [rlo,rhi]x[vlo,vhi]; reads valid slots, writes phantom slots
// -> race-free without an internal barrier. Block-uniform early-out.
template<int NR, int NC>
__device__ __forceinline__ void replicate_fill(float* buf, int rlo, int rhi,
                                               int vlo, int vhi, int tid)
{
    if (rlo == 0 && vlo == 0 && rhi == NR - 1 && vhi == NC - 1) return;
    for (int t = tid; t < NR * NC; t += 256) {
        const int r = t / NC, v = t - r * NC;
        const int rs = min(max(r, rlo), rhi);
        const int vs = min(max(v, vlo), vhi);
        if (rs != r || vs != v) buf[r * NC + v] = buf[rs * NC + vs];
    }
}

// Build 6-wide window row (cols c-1 .. c+4) from 3 aligned b128 quads.
__device__ __forceinline__ void mkrow6(const float* p, float* w6)
{
    const float4 L = *(const float4*)(p - 4);
    const float4 M = *(const float4*)(p);
    const float4 R = *(const float4*)(p + 4);
    w6[0] = L.w; w6[1] = M.x; w6[2] = M.y; w6[3] = M.z; w6[4] = M.w;
    w6[5] = R.x;
}

// One bilateral pass over a tile held in LDS.
// Unit t -> (row r, quad q); center quad at src[(r+2)*SST + 4q+4].
template<int NQ, int NR, int SST, int DSTST, bool TOG>
__device__ __forceinline__ void bilat_tile_pass(
    const float* __restrict__ src, float* __restrict__ dst,
    float* __restrict__ gout, int W,
    int tid, float ncr, float nax, float nay, bool prune)
{
    const v2f ncr2 = {ncr, ncr};
    for (int t = tid; t < NQ * NR; t += 256) {
        const int r = t / NQ;
        const int q = t - r * NQ;
        const float* cp = src + (r + 2) * SST + 4 * q + 4;

        if (prune) {
            // ---- packed 3x3 core: 16 tap-pairs = 80 pk ops + 32 exp ----
            float wm[6], wc[6], wp[6];
            mkrow6(cp, wc);
            mkrow6(cp - SST, wm);
            mkrow6(cp + SST, wp);

            v2f c01 = {wc[1], wc[2]}, c23 = {wc[3], wc[4]};
            v2f n01 = c01, n23 = c23;               // center tap, w == 1
            v2f d01 = {1.f, 1.f}, d23 = {1.f, 1.f};

            auto tap_pair = [&](v2f nb, v2f ce, v2f& nu, v2f& de, float b) {
                v2f d  = nb - ce;                                   // pk_add
                v2f tt = __builtin_elementwise_fma(d * d, ncr2,
                                                   (v2f){b, b});    // pk_mul+pk_fma
                v2f w  = {EXP2(tt.x), EXP2(tt.y)};
                nu = __builtin_elementwise_fma(w, nb, nu);          // pk_fma
                de += w;                                            // pk_add
            };
            auto row_taps = [&](const float* w6, float bm, float b0,
                                float bp, bool skip0) {
                tap_pair((v2f){w6[0], w6[1]}, c01, n01, d01, bm);   // dc=-1
                tap_pair((v2f){w6[2], w6[3]}, c23, n23, d23, bm);
                if (!skip0) {
                    tap_pair((v2f){w6[1], w6[2]}, c01, n01, d01, b0); // dc=0
                    tap_pair((v2f){w6[3], w6[4]}, c23, n23, d23, b0);
                }
                tap_pair((v2f){w6[2], w6[3]}, c01, n01, d01, bp);   // dc=+1
                tap_pair((v2f){w6[4], w6[5]}, c23, n23, d23, bp);
            };

            const float bd = nax + nay;
            row_taps(wc, nay, 0.0f, nay, true);     // dr = 0 (center folded)
            row_taps(wm, bd, nax, bd, false);       // dr = -1
            row_taps(wp, bd, nax, bd, false);       // dr = +1

            float4 o;
            o.x = n01.x * RCP(d01.x);
            o.y = n01.y * RCP(d01.y);
            o.z = n23.x * RCP(d23.x);
            o.w = n23.y * RCP(d23.y);
            if (TOG) *(float4*)(gout + r * W + 4 * q) = o;
            else     *(float4*)(dst + r * DSTST + 4 * q) = o;
        } else {
            // ---- generic 5x5 with per-tap uniform pruning (cold path) ----
            const float4 M0 = *(const float4*)cp;
            float cen[4] = {M0.x, M0.y, M0.z, M0.w};
            float num[4] = {M0.x, M0.y, M0.z, M0.w};
            float den[4] = {1.f, 1.f, 1.f, 1.f};
            #pragma unroll
            for (int dr = -2; dr <= 2; ++dr) {
                const float ra = (float)(dr * dr) * nax;
                const float rbest = dr ? ra : nay;
                if (rbest < TH2) continue;
                const float* rp2 = cp + dr * SST;
                const float4 Lq = *(const float4*)(rp2 - 4);
                const float4 Mq = *(const float4*)(rp2);
                const float4 Rq = *(const float4*)(rp2 + 4);
                const float w8[8] = {Lq.z, Lq.w, Mq.x, Mq.y, Mq.z, Mq.w,
                                     Rq.x, Rq.y};
                #pragma unroll
                for (int dc = -2; dc <= 2; ++dc) {
                    if (dr == 0 && dc == 0) continue;
                    const float b = ra + (float)(dc * dc) * nay;
                    if (b < TH2) continue;
                    #pragma unroll
                    for (int j = 0; j < 4; ++j) {
                        const float nb = w8[2 + j + dc];
                        const float d  = nb - cen[j];
                        const float tt = fmaf(d * d, ncr, b);
                        const float w  = EXP2(tt);
                        num[j] = fmaf(w, nb, num[j]);
                        den[j] += w;
                    }
                }
            }
            float4 o;
            o.x = num[0] * RCP(den[0]);
            o.y = num[1] * RCP(den[1]);
            o.z = num[2] * RCP(den[2]);
            o.w = num[3] * RCP(den[3]);
            if (TOG) *(float4*)(gout + r * W + 4 * q) = o;
            else     *(float4*)(dst + r * DSTST + 4 * q) = o;
        }
    }
}

__global__ __launch_bounds__(256)
void bilat3_fused(const float* __restrict__ in, float* __restrict__ out,
                  const float* __restrict__ sxyz, const float* __restrict__ srr,
                  int H, int W)
{
    __shared__ __align__(16) float buf0[S0R * S0C];   // 16192 B
    __shared__ __align__(16) float buf1[S1R * S1C];   // 13440 B -> 29.6 KB

    const int tid = threadIdx.x;
    const int X0 = blockIdx.x * TILE_X;
    const int Y0 = blockIdx.y * TILE_Y;
    const size_t img_off = (size_t)blockIdx.z * (size_t)H * (size_t)W;
    const float* __restrict__ img = in + img_off;

    // per-pass constants, -log2e pre-folded
    const float L2E = 1.4426950408889634f;
    float ncr[3], nax[3], nay[3];
    bool prune[3];
    #pragma unroll
    for (int p = 0; p < 3; ++p) {
        const float sx = sxyz[2 * p], sy = sxyz[2 * p + 1], sr = srr[p];
        ncr[p] = -0.5f / (sr * sr) * L2E;
        nax[p] = -0.5f / (sx * sx) * L2E;
        nay[p] = -0.5f / (sy * sy) * L2E;
        prune[p] = (4.f * nax[p] < TH2) && (4.f * nay[p] < TH2);
    }

    // ---- stage buf0: replicate-clamped input aperture ----
    {
        const int NQ0 = S0C / 4;  // 23 quads/row
        for (int t = tid; t < S0R * NQ0; t += 256) {
            const int r = t / NQ0, k = t - r * NQ0;
            const int gy = Y0 - 6 + r;
            const int gx = X0 - 12 + 4 * k;
            float4 v;
            if (gy >= 0 && gy < H && gx >= 0 && gx + 3 < W) {
                v = *(const float4*)(img + (size_t)gy * W + gx);  // aligned
            } else {
                const size_t rb = (size_t)min(max(gy, 0), H - 1) * W;
                v.x = img[rb + min(max(gx    , 0), W - 1)];
                v.y = img[rb + min(max(gx + 1, 0), W - 1)];
                v.z = img[rb + min(max(gx + 2, 0), W - 1)];
                v.w = img[rb + min(max(gx + 3, 0), W - 1)];
            }
            *(float4*)(buf0 + r * S0C + 4 * k) = v;
        }
    }
    __syncthreads();

    // ---- pass 1: buf0 -> buf1 ----
    bilat_tile_pass<S1C / 4, S1R, S0C, S1C, false>(
        buf0, buf1, nullptr, W, tid, ncr[0], nax[0], nay[0], prune[0]);
    __syncthreads();
    replicate_fill<S1R, S1C>(buf1,
        max(0, 4 - Y0), min(S1R - 1, (H - 1) - (Y0 - 4)),
        max(0, 8 - X0), min(S1C - 1, (W - 1) - (X0 - 8)), tid);
    __syncthreads();

    // ---- pass 2: buf1 -> buf2 (aliases buf0; staged input is dead) ----
    float* buf2 = buf0;
    bilat_tile_pass<S2C / 4, S2R, S1C, S2C, false>(
        buf1, buf2, nullptr, W, tid, ncr[1], nax[1], nay[1], prune[1]);
    __syncthreads();
    replicate_fill<S2R, S2C>(buf2,
        max(0, 2 - Y0), min(S2R - 1, (H - 1) - (Y0 - 2)),
        max(0, 4 - X0), min(S2C - 1, (W - 1) - (X0 - 4)), tid);
    __syncthreads();

    // ---- pass 3: buf2 -> global (512 units = 2 x 256) ----
    float* gout = out + img_off + (size_t)Y0 * W + X0;
    bilat_tile_pass<TILE_X / 4, TILE_Y, S2C, 0, true>(
        buf2, nullptr, gout, W, tid, ncr[2], nax[2], nay[2], prune[2]);
}

extern "C" void kernel_launch(void* const* d_in, const int* in_sizes, int n_in,
                              void* d_out, int out_size, void* d_ws, size_t ws_size,
                              hipStream_t stream)
{
    const float* x    = (const float*)d_in[0];
    const float* sxyz = (const float*)d_in[1];   // [3,2]
    const float* sr   = (const float*)d_in[2];   // [3]
    float* out = (float*)d_out;
    (void)d_ws; (void)ws_size;

    const int H = 512, W = 512;
    const int BC = in_sizes[0] / (H * W);        // 32

    dim3 block(256);
    dim3 grid(W / TILE_X, H / TILE_Y, BC);       // 8 x 16 x 32 = 4096 blocks

    bilat3_fused<<<grid, block, 0, stream>>>(x, out, sxyz, sr, H, W);
}